// Round 5
// baseline (199.922 us; speedup 1.0000x reference)
//
#include <hip/hip_runtime.h>

typedef __bf16 bf16_t;
typedef __bf16 bf16x4_t __attribute__((ext_vector_type(4)));
typedef __bf16 bf16x8 __attribute__((ext_vector_type(8)));
typedef float f32x4 __attribute__((ext_vector_type(4)));

#define NH 8
#define DH 32
#define QL 256
#define KL 256
#define CIN 64
#define HD 256  // NH*DH

__device__ __forceinline__ bf16_t f2bf(float x) { return (bf16_t)x; }

__device__ __forceinline__ f32x4 mfma16(bf16x8 a, bf16x8 b, f32x4 c) {
    return __builtin_amdgcn_mfma_f32_16x16x32_bf16(a, b, c, 0, 0, 0);
}

__device__ __forceinline__ bf16x8 cvt8(const float* __restrict__ p) {
    bf16x8 r;
#pragma unroll
    for (int j = 0; j < 8; ++j) r[j] = f2bf(p[j]);
    return r;
}

// ============================ fast path =====================================
// Phase 1: K/V projection for all (s,h) into MFMA-ready bf16 layouts.
// grid (128 s, 2 which): which=0 -> Kws[s][h][kv][d], which=1 -> VTws[s][h][d][kv]
__launch_bounds__(256, 4)
__global__ void proj_kv(const float* __restrict__ Xkv,
                        const float* __restrict__ Wk,
                        const float* __restrict__ Wv,
                        bf16_t* __restrict__ Kws,
                        bf16_t* __restrict__ VTws) {
    const int s     = blockIdx.x;
    const int which = blockIdx.y;
    const int tid   = threadIdx.x;
    const int lane  = tid & 63;
    const int w     = tid >> 6;
    const int quad  = lane >> 4;
    const int l16   = lane & 15;
    const f32x4 vzero = {0.f, 0.f, 0.f, 0.f};

    // W^T staged: sW[n=hd][k=cin], 256x72 bf16 = 36.9 KB
    __shared__ __attribute__((aligned(16))) bf16_t sW[HD][CIN + 8];
    const float* __restrict__ W = which ? Wv : Wk;
#pragma unroll
    for (int it = 0; it < 16; ++it) {
        const int idx = it * 256 + tid;
        const int k   = idx >> 6;
        const int c4  = (idx & 63) << 2;
        const f32x4 w4 = *(const f32x4*)&W[k * HD + c4];
#pragma unroll
        for (int j = 0; j < 4; ++j) sW[c4 + j][k] = f2bf(w4[j]);
    }
    __syncthreads();

    if (which == 0) {
        // K = Xkv_s(256x64) @ Wk(64x256): A = X rows, B = sW^T reads
#pragma unroll 1
        for (int mt = 0; mt < 4; ++mt) {
            const int m0 = w * 64 + mt * 16;
            const float* xp = &Xkv[(s * KL + m0 + l16) * CIN + quad * 8];
            const bf16x8 a0 = cvt8(xp);
            const bf16x8 a1 = cvt8(xp + 32);
#pragma unroll
            for (int nt = 0; nt < 16; ++nt) {
                const bf16x8 b0 = *(const bf16x8*)&sW[nt * 16 + l16][quad * 8];
                const bf16x8 b1 = *(const bf16x8*)&sW[nt * 16 + l16][32 + quad * 8];
                f32x4 c = mfma16(a0, b0, vzero);
                c = mfma16(a1, b1, c);
                // C/D: row(kv)=m0+quad*4+r, col(n)=nt*16+l16; h=nt>>1, d=(nt&1)*16+l16
                bf16_t* dst = &Kws[((size_t)(s * NH + (nt >> 1)) * KL) * DH + (nt & 1) * 16 + l16];
#pragma unroll
                for (int r = 0; r < 4; ++r)
                    dst[(m0 + quad * 4 + r) * DH] = f2bf(c[r]);
            }
        }
    } else {
        // V^T = Wv^T(256x64) @ Xkv_s^T(64x256): A = sW^T reads, B = X rows
#pragma unroll 1
        for (int ntl = 0; ntl < 4; ++ntl) {
            const int n0 = w * 64 + ntl * 16;
            const float* xp = &Xkv[(s * KL + n0 + l16) * CIN + quad * 8];
            const bf16x8 b0 = cvt8(xp);
            const bf16x8 b1 = cvt8(xp + 32);
#pragma unroll
            for (int mt = 0; mt < 16; ++mt) {
                const bf16x8 a0 = *(const bf16x8*)&sW[mt * 16 + l16][quad * 8];
                const bf16x8 a1 = *(const bf16x8*)&sW[mt * 16 + l16][32 + quad * 8];
                f32x4 c = mfma16(a0, b0, vzero);
                c = mfma16(a1, b1, c);
                // C/D: row(m=hd)=mt*16+quad*4+r, col(kv)=n0+l16
                bf16_t* dst = &VTws[((size_t)(s * NH + (mt >> 1)) * DH + (mt & 1) * 16 + quad * 4) * KL + n0 + l16];
#pragma unroll
                for (int r = 0; r < 4; ++r)
                    dst[r * KL] = f2bf(c[r]);
            }
        }
    }
}

// Phase 2: attention. grid (128 s, 4 qt, 8 h) = 4096 blocks; wave = ONE 16-row
// q-tile. K/V/bias come straight from global (L2-hot); LDS only for the two
// per-wave layout round-trips (Q b-frag, P^T a-frag). 18.5 KB LDS.
__launch_bounds__(256, 4)
__global__ void attn_ws(const float* __restrict__ Xq,
                        const float* __restrict__ Mask,
                        const float* __restrict__ Bias,
                        const float* __restrict__ Wq,
                        const bf16_t* __restrict__ Kws,
                        const bf16_t* __restrict__ VTws,
                        bf16_t* __restrict__ Ows) {
    const int s    = blockIdx.x;
    const int qt   = blockIdx.y;
    const int h    = blockIdx.z;
    const int tid  = threadIdx.x;
    const int lane = tid & 63;
    const int w    = tid >> 6;
    const int quad = lane >> 4;
    const int l16  = lane & 15;
    const f32x4 vzero = {0.f, 0.f, 0.f, 0.f};
    const float scale = 0.17677669529663687f;  // 1/sqrt(32)

    __shared__ __attribute__((aligned(16))) bf16_t sWqT[DH][CIN + 8];   // 4.6 KB
    __shared__ __attribute__((aligned(16))) bf16_t sQs[4][16][DH + 8];  // 5 KB
    __shared__ __attribute__((aligned(16))) bf16_t sPT[4][16][64 + 8];  // 9.2 KB

    // stage Wq head-slice transposed (coalesced float4)
#pragma unroll
    for (int it = 0; it < 2; ++it) {
        const int idx = it * 256 + tid;
        const int k   = idx >> 3;
        const int c4  = (idx & 7) << 2;
        const f32x4 w4 = *(const f32x4*)&Wq[k * HD + h * DH + c4];
#pragma unroll
        for (int j = 0; j < 4; ++j) sWqT[c4 + j][k] = f2bf(w4[j]);
    }
    __syncthreads();

    // ---- q projection for this wave's 16 rows -> B-frag bq ----
    const int q0 = qt * 64 + w * 16;
    bf16x8 bq;
    {
        bf16x8 bwq[2][2];
#pragma unroll
        for (int nt = 0; nt < 2; ++nt)
#pragma unroll
            for (int ks = 0; ks < 2; ++ks)
                bwq[nt][ks] = *(const bf16x8*)&sWqT[nt * 16 + l16][ks * 32 + quad * 8];
        const float* xp = &Xq[(s * QL + q0 + l16) * CIN + quad * 8];
        const bf16x8 a0 = cvt8(xp);
        const bf16x8 a1 = cvt8(xp + 32);
        f32x4 c0 = vzero, c1 = vzero;
        c0 = mfma16(a0, bwq[0][0], c0);
        c0 = mfma16(a1, bwq[0][1], c0);
        c1 = mfma16(a0, bwq[1][0], c1);
        c1 = mfma16(a1, bwq[1][1], c1);
#pragma unroll
        for (int nt = 0; nt < 2; ++nt) {
            const f32x4 c = nt ? c1 : c0;
#pragma unroll
            for (int r = 0; r < 4; ++r)
                sQs[w][quad * 4 + r][nt * 16 + l16] = f2bf(c[r] * scale);
        }
        // same-wave DS ops are in-order
        bq = *(const bf16x8*)&sQs[w][l16][quad * 8];
    }

    const bf16_t* __restrict__ Kb = &Kws[(size_t)(s * NH + h) * KL * DH];
    const bf16_t* __restrict__ Vb = &VTws[(size_t)(s * NH + h) * DH * KL];

    // ---- scores S' = K·Q^T: C/D row(kv)=quad*4+r, col(q)=l16 ----
    f32x4 sv[16];
#pragma unroll
    for (int ct = 0; ct < 16; ++ct) {
        const bf16x8 ak = *(const bf16x8*)&Kb[(ct * 16 + l16) * DH + quad * 8];
        sv[ct] = mfma16(ak, bq, vzero);
    }
    // bias (float4 along kv) + mask
    const float* bbase = &Bias[(size_t)(h * QL + q0 + l16) * KL];
#pragma unroll
    for (int ct = 0; ct < 16; ++ct) {
        const f32x4 b4 = *(const f32x4*)&bbase[ct * 16 + quad * 4];
        const f32x4 m4 = *(const f32x4*)&Mask[s * KL + ct * 16 + quad * 4];
        sv[ct] = sv[ct] + b4 + (m4 - 1.0f) * 1.0e9f;
    }
    // softmax over kv: 64 per-lane values + xor 16, 32 across quads
    float mx = -1e30f;
#pragma unroll
    for (int ct = 0; ct < 16; ++ct)
#pragma unroll
        for (int r = 0; r < 4; ++r) mx = fmaxf(mx, sv[ct][r]);
    mx = fmaxf(mx, __shfl_xor(mx, 16, 64));
    mx = fmaxf(mx, __shfl_xor(mx, 32, 64));
    float sum = 0.f;
#pragma unroll
    for (int ct = 0; ct < 16; ++ct)
#pragma unroll
        for (int r = 0; r < 4; ++r) {
            const float e = __expf(sv[ct][r] - mx);
            sv[ct][r] = e;
            sum += e;
        }
    sum += __shfl_xor(sum, 16, 64);
    sum += __shfl_xor(sum, 32, 64);
    const float rs = 1.0f / sum;

    // ---- PV in four 64-kv chunks: normalized P^T -> sPT -> A-frags ----
    f32x4 o0 = vzero, o1 = vzero;
#pragma unroll
    for (int c = 0; c < 4; ++c) {
#pragma unroll
        for (int cc = 0; cc < 4; ++cc) {
            const int ct = c * 4 + cc;
            bf16x4_t pv;
#pragma unroll
            for (int r = 0; r < 4; ++r) pv[r] = f2bf(sv[ct][r] * rs);
            *(bf16x4_t*)&sPT[w][l16][cc * 16 + quad * 4] = pv;
        }
#pragma unroll
        for (int ks = 0; ks < 2; ++ks) {
            const bf16x8 ap  = *(const bf16x8*)&sPT[w][l16][ks * 32 + quad * 8];
            const int kg     = c * 64 + ks * 32 + quad * 8;
            const bf16x8 bv0 = *(const bf16x8*)&Vb[l16 * KL + kg];
            const bf16x8 bv1 = *(const bf16x8*)&Vb[(16 + l16) * KL + kg];
            o0 = mfma16(ap, bv0, o0);
            o1 = mfma16(ap, bv1, o1);
        }
    }
    // O tile: row(q)=quad*4+r, col(d)=l16 per nt
#pragma unroll
    for (int nt = 0; nt < 2; ++nt) {
        const f32x4 o = nt ? o1 : o0;
#pragma unroll
        for (int r = 0; r < 4; ++r) {
            const int row = q0 + quad * 4 + r;
            Ows[(size_t)(s * QL + row) * HD + h * DH + nt * 16 + l16] = f2bf(o[r]);
        }
    }
}

// ====================== fallback path (proven, r4) ==========================
__launch_bounds__(256, 2)
__global__ void attn_h(const float* __restrict__ Xq,
                       const float* __restrict__ Xkv,
                       const float* __restrict__ Mask,
                       const float* __restrict__ Bias,
                       const float* __restrict__ Wq,
                       const float* __restrict__ Wk,
                       const float* __restrict__ Wv,
                       bf16_t* __restrict__ Ows) {
    const int h    = blockIdx.x;
    const int s    = blockIdx.y;
    const int tid  = threadIdx.x;
    const int lane = tid & 63;
    const int w    = tid >> 6;
    const int quad = lane >> 4;
    const int l16  = lane & 15;

    __shared__ __attribute__((aligned(16))) bf16_t sWT[3][DH][CIN + 8];
    __shared__ __attribute__((aligned(16))) bf16_t sK[KL][DH + 8];
    __shared__ __attribute__((aligned(16))) bf16_t sVT[DH][KL + 8];
    __shared__ __attribute__((aligned(16))) bf16_t sQs[4][16][DH + 8];
    __shared__ __attribute__((aligned(16))) bf16_t sPT[4][16][64 + 8];
    __shared__ float sMask[KL];

    const float scale = 0.17677669529663687f;
    const f32x4 vzero = {0.f, 0.f, 0.f, 0.f};

#pragma unroll
    for (int it = 0; it < 2; ++it) {
        const int idx = it * 256 + tid;
        const int row = idx >> 3;
        const int c4  = (idx & 7) * 4;
        const int ga  = row * HD + h * DH + c4;
        const f32x4 q4 = *(const f32x4*)&Wq[ga];
        const f32x4 k4 = *(const f32x4*)&Wk[ga];
        const f32x4 v4 = *(const f32x4*)&Wv[ga];
#pragma unroll
        for (int j = 0; j < 4; ++j) {
            sWT[0][c4 + j][row] = f2bf(q4[j]);
            sWT[1][c4 + j][row] = f2bf(k4[j]);
            sWT[2][c4 + j][row] = f2bf(v4[j]);
        }
    }
    sMask[tid] = (Mask[s * KL + tid] - 1.0f) * 1.0e9f;
    __syncthreads();

    bf16x8 bwq[2][2], bwk[2][2], bwv[2][2];
#pragma unroll
    for (int nt = 0; nt < 2; ++nt)
#pragma unroll
        for (int ks = 0; ks < 2; ++ks) {
            bwq[nt][ks] = *(const bf16x8*)&sWT[0][nt * 16 + l16][ks * 32 + quad * 8];
            bwk[nt][ks] = *(const bf16x8*)&sWT[1][nt * 16 + l16][ks * 32 + quad * 8];
            bwv[nt][ks] = *(const bf16x8*)&sWT[2][nt * 16 + l16][ks * 32 + quad * 8];
        }

    bf16x8 bq[4];
#pragma unroll
    for (int i = 0; i < 4; ++i) {
        const int r0 = w * 64 + i * 16;
        const float* xp = &Xq[(s * QL + r0 + l16) * CIN + quad * 8];
        const bf16x8 a0 = cvt8(xp);
        const bf16x8 a1 = cvt8(xp + 32);
        f32x4 c0 = vzero, c1 = vzero;
        c0 = mfma16(a0, bwq[0][0], c0);
        c0 = mfma16(a1, bwq[0][1], c0);
        c1 = mfma16(a0, bwq[1][0], c1);
        c1 = mfma16(a1, bwq[1][1], c1);
#pragma unroll
        for (int nt = 0; nt < 2; ++nt) {
            const f32x4 c = nt ? c1 : c0;
#pragma unroll
            for (int r = 0; r < 4; ++r)
                sQs[w][quad * 4 + r][nt * 16 + l16] = f2bf(c[r] * scale);
        }
        bq[i] = *(const bf16x8*)&sQs[w][l16][quad * 8];
    }

#pragma unroll
    for (int t = 0; t < 4; ++t) {
        const int r0 = w * 64 + t * 16;
        const float* xp = &Xkv[(s * KL + r0 + l16) * CIN + quad * 8];
        const bf16x8 a0 = cvt8(xp);
        const bf16x8 a1 = cvt8(xp + 32);
        f32x4 k0 = vzero, k1 = vzero, v0 = vzero, v1 = vzero;
        k0 = mfma16(a0, bwk[0][0], k0);
        k0 = mfma16(a1, bwk[0][1], k0);
        k1 = mfma16(a0, bwk[1][0], k1);
        k1 = mfma16(a1, bwk[1][1], k1);
        v0 = mfma16(a0, bwv[0][0], v0);
        v0 = mfma16(a1, bwv[0][1], v0);
        v1 = mfma16(a0, bwv[1][0], v1);
        v1 = mfma16(a1, bwv[1][1], v1);
#pragma unroll
        for (int nt = 0; nt < 2; ++nt) {
            const f32x4 kc = nt ? k1 : k0;
            const f32x4 vc = nt ? v1 : v0;
#pragma unroll
            for (int r = 0; r < 4; ++r) {
                const int row = r0 + quad * 4 + r;
                sK[row][nt * 16 + l16]  = f2bf(kc[r]);
                sVT[nt * 16 + l16][row] = f2bf(vc[r]);
            }
        }
    }
    __syncthreads();

#pragma unroll 1
    for (int i = 0; i < 4; ++i) {
        const int qr0 = w * 64 + i * 16;
        f32x4 sv[16];
#pragma unroll
        for (int ct = 0; ct < 16; ++ct) {
            const bf16x8 ak = *(const bf16x8*)&sK[ct * 16 + l16][quad * 8];
            sv[ct] = mfma16(ak, bq[i], vzero);
        }
        const float* bbase = &Bias[(h * QL + qr0 + l16) * KL];
#pragma unroll
        for (int ct = 0; ct < 16; ++ct) {
            const f32x4 b4 = *(const f32x4*)&bbase[ct * 16 + quad * 4];
            const f32x4 m4 = *(const f32x4*)&sMask[ct * 16 + quad * 4];
            sv[ct] = sv[ct] + b4 + m4;
        }
        float mx = -1e30f;
#pragma unroll
        for (int ct = 0; ct < 16; ++ct)
#pragma unroll
            for (int r = 0; r < 4; ++r) mx = fmaxf(mx, sv[ct][r]);
        mx = fmaxf(mx, __shfl_xor(mx, 16, 64));
        mx = fmaxf(mx, __shfl_xor(mx, 32, 64));
        float sum = 0.f;
#pragma unroll
        for (int ct = 0; ct < 16; ++ct)
#pragma unroll
            for (int r = 0; r < 4; ++r) {
                const float e = __expf(sv[ct][r] - mx);
                sv[ct][r] = e;
                sum += e;
            }
        sum += __shfl_xor(sum, 16, 64);
        sum += __shfl_xor(sum, 32, 64);
        const float rs = 1.0f / sum;

        f32x4 o0 = vzero, o1 = vzero;
#pragma unroll
        for (int c = 0; c < 4; ++c) {
#pragma unroll
            for (int cc = 0; cc < 4; ++cc) {
                const int ct = c * 4 + cc;
                bf16x4_t pv;
#pragma unroll
                for (int r = 0; r < 4; ++r) pv[r] = f2bf(sv[ct][r] * rs);
                *(bf16x4_t*)&sPT[w][l16][cc * 16 + quad * 4] = pv;
            }
#pragma unroll
            for (int ks = 0; ks < 2; ++ks) {
                const bf16x8 ap  = *(const bf16x8*)&sPT[w][l16][ks * 32 + quad * 8];
                const int kg     = c * 64 + ks * 32 + quad * 8;
                const bf16x8 bv0 = *(const bf16x8*)&sVT[l16][kg];
                const bf16x8 bv1 = *(const bf16x8*)&sVT[16 + l16][kg];
                o0 = mfma16(ap, bv0, o0);
                o1 = mfma16(ap, bv1, o1);
            }
        }
#pragma unroll
        for (int nt = 0; nt < 2; ++nt) {
            const f32x4 o = nt ? o1 : o0;
#pragma unroll
            for (int r = 0; r < 4; ++r) {
                const int row = qr0 + quad * 4 + r;
                Ows[(s * QL + row) * HD + h * DH + nt * 16 + l16] = f2bf(o[r]);
            }
        }
    }
}

// Phase 3: out[32768,64] = Ows[32768,256](bf16) @ wo[256,64] + bo
__launch_bounds__(256, 4)
__global__ void outproj_kernel(const bf16_t* __restrict__ Ows,
                               const float* __restrict__ Wo,
                               const float* __restrict__ Bo,
                               float* __restrict__ Out) {
    const int tid  = threadIdx.x;
    const int lane = tid & 63;
    const int w    = tid >> 6;
    const int quad = lane >> 4;
    const int l16  = lane & 15;
    const int R    = blockIdx.x * 128;

    __shared__ __attribute__((aligned(16))) bf16_t sWoT[CIN][HD + 8];
    __shared__ float sBo[CIN];

    // stage Wo transposed with float4 loads (16 per thread)
#pragma unroll
    for (int it = 0; it < 16; ++it) {
        const int idx = it * 256 + tid;
        const int kk  = idx >> 4;
        const int c4  = (idx & 15) << 2;
        const f32x4 w4 = *(const f32x4*)&Wo[kk * CIN + c4];
#pragma unroll
        for (int j = 0; j < 4; ++j) sWoT[c4 + j][kk] = f2bf(w4[j]);
    }
    if (tid < CIN) sBo[tid] = Bo[tid];
    __syncthreads();

    const f32x4 vzero = {0.f, 0.f, 0.f, 0.f};
#pragma unroll 1
    for (int i = 0; i < 2; ++i) {
        const int mr0 = R + w * 32 + i * 16;
        bf16x8 a[8];
#pragma unroll
        for (int ks = 0; ks < 8; ++ks)
            a[ks] = *(const bf16x8*)&Ows[(size_t)(mr0 + l16) * HD + ks * 32 + quad * 8];
        f32x4 acc[4];
#pragma unroll
        for (int nt = 0; nt < 4; ++nt) acc[nt] = vzero;
#pragma unroll
        for (int ks = 0; ks < 8; ++ks)
#pragma unroll
            for (int nt = 0; nt < 4; ++nt) {
                const bf16x8 b = *(const bf16x8*)&sWoT[nt * 16 + l16][ks * 32 + quad * 8];
                acc[nt] = mfma16(a[ks], b, acc[nt]);
            }
#pragma unroll
        for (int nt = 0; nt < 4; ++nt) {
            const float bo = sBo[nt * 16 + l16];
#pragma unroll
            for (int r = 0; r < 4; ++r)
                Out[(mr0 + quad * 4 + r) * CIN + nt * 16 + l16] = acc[nt][r] + bo;
        }
    }
}

extern "C" void kernel_launch(void* const* d_in, const int* in_sizes, int n_in,
                              void* d_out, int out_size, void* d_ws, size_t ws_size,
                              hipStream_t stream) {
    const float* Xq   = (const float*)d_in[0];
    const float* Xkv  = (const float*)d_in[1];
    const float* Mask = (const float*)d_in[2];
    const float* Bias = (const float*)d_in[3];
    const float* Wq   = (const float*)d_in[4];
    const float* Wk   = (const float*)d_in[5];
    const float* Wv   = (const float*)d_in[6];
    const float* Wo   = (const float*)d_in[7];
    const float* Bo   = (const float*)d_in[8];
    float* Out = (float*)d_out;

    const size_t SEG = 16777216;  // 16 MB per buffer
    if (ws_size >= 3 * SEG) {
        bf16_t* Kws  = (bf16_t*)d_ws;
        bf16_t* VTws = (bf16_t*)((char*)d_ws + SEG);
        bf16_t* Ows  = (bf16_t*)((char*)d_ws + 2 * SEG);
        proj_kv<<<dim3(128, 2), 256, 0, stream>>>(Xkv, Wk, Wv, Kws, VTws);
        attn_ws<<<dim3(128, 4, NH), 256, 0, stream>>>(Xq, Mask, Bias, Wq, Kws, VTws, Ows);
        outproj_kernel<<<256, 256, 0, stream>>>(Ows, Wo, Bo, Out);
    } else {
        bf16_t* Ows = (bf16_t*)d_ws;
        attn_h<<<dim3(NH, 128), 256, 0, stream>>>(Xq, Xkv, Mask, Bias, Wq, Wk, Wv, Ows);
        outproj_kernel<<<256, 256, 0, stream>>>(Ows, Wo, Bo, Out);
    }
}